// Round 1
// baseline (7029.697 us; speedup 1.0000x reference)
//
#include <hip/hip_runtime.h>

// GCN 2-layer forward. All fp32.
// ws layout (floats): [deg_int N][s1 48N][s2 32N][dinv N][g1 48N][g2 32N] = 162N

__global__ void k_degree(const int* __restrict__ col, int E, int* __restrict__ deg) {
    int e = blockIdx.x * blockDim.x + threadIdx.x;
    if (e < E) atomicAdd(&deg[col[e]], 1);
}

// h1 = x.T @ W1 ; g1[n,:] = dinv[n] * h1[n,:] ; also writes dinv[n]
__global__ void k_gemm1(const float* __restrict__ x, const float* __restrict__ W1,
                        const int* __restrict__ deg, float* __restrict__ dinv,
                        float* __restrict__ g1, int N) {
    __shared__ float Ws[48 * 48];
    for (int i = threadIdx.x; i < 48 * 48; i += blockDim.x) Ws[i] = W1[i];
    __syncthreads();
    int n = blockIdx.x * blockDim.x + threadIdx.x;
    if (n >= N) return;
    float acc[48];
#pragma unroll
    for (int j = 0; j < 48; j++) acc[j] = 0.f;
    for (int k = 0; k < 48; k++) {
        float xv = x[(size_t)k * N + n];  // coalesced across lanes
#pragma unroll
        for (int j = 0; j < 48; j++) acc[j] += xv * Ws[k * 48 + j];  // LDS broadcast
    }
    float dv = rsqrtf((float)(deg[n] + 1));  // +1 self-loop; deg>=1 always
    dinv[n] = dv;
    float* gp = g1 + (size_t)n * 48;
#pragma unroll
    for (int j = 0; j < 48; j++) gp[j] = dv * acc[j];
}

// s[col[e], :] += g[row[e], :]   (one thread per edge, F floats, float4 gather)
template <int F>
__global__ void k_scatter(const int* __restrict__ row, const int* __restrict__ col,
                          const float* __restrict__ g, float* __restrict__ s, int E) {
    int e = blockIdx.x * blockDim.x + threadIdx.x;
    if (e >= E) return;
    int r = row[e], c = col[e];
    const float4* gp = (const float4*)(g + (size_t)r * F);  // F*4 bytes, 16B-aligned
    float* sp = s + (size_t)c * F;
#pragma unroll
    for (int q = 0; q < F / 4; q++) {
        float4 v = gp[q];
        atomicAdd(sp + 4 * q + 0, v.x);
        atomicAdd(sp + 4 * q + 1, v.y);
        atomicAdd(sp + 4 * q + 2, v.z);
        atomicAdd(sp + 4 * q + 3, v.w);
    }
}

// a1[n,k] = relu(dinv[n]*(s1+g1)[n,k] + b1[k])  (layer-1 epilogue, fused)
// g2[n,:] = dinv[n] * (a1[n,:] @ W2)
__global__ void k_gemm2(const float* __restrict__ s1, const float* __restrict__ g1,
                        const float* __restrict__ dinv, const float* __restrict__ b1,
                        const float* __restrict__ W2, float* __restrict__ g2, int N) {
    __shared__ float Ws[48 * 32];
    __shared__ float bs[48];
    for (int i = threadIdx.x; i < 48 * 32; i += blockDim.x) Ws[i] = W2[i];
    if (threadIdx.x < 48) bs[threadIdx.x] = b1[threadIdx.x];
    __syncthreads();
    int n = blockIdx.x * blockDim.x + threadIdx.x;
    if (n >= N) return;
    float dv = dinv[n];
    float acc[32];
#pragma unroll
    for (int j = 0; j < 32; j++) acc[j] = 0.f;
    const float* sp = s1 + (size_t)n * 48;
    const float* gp = g1 + (size_t)n * 48;
    for (int k = 0; k < 48; k++) {
        float a = dv * (sp[k] + gp[k]) + bs[k];
        a = a > 0.f ? a : 0.f;
#pragma unroll
        for (int j = 0; j < 32; j++) acc[j] += a * Ws[k * 32 + j];
    }
    float* op = g2 + (size_t)n * 32;
#pragma unroll
    for (int j = 0; j < 32; j++) op[j] = dv * acc[j];
}

// out[j] = sum_n onehot[n]*(dinv[n]*(s2+g2)[n,j] + b2[j])
//        = sum_n onehot[n]*dinv[n]*(s2+g2)[n,j]  +  b2[j]*sum_n onehot[n]
__global__ void k_final(const float* __restrict__ s2, const float* __restrict__ g2,
                        const float* __restrict__ dinv, const float* __restrict__ onehot,
                        const float* __restrict__ b2, float* __restrict__ out, int N) {
    float acc[32];
#pragma unroll
    for (int j = 0; j < 32; j++) acc[j] = 0.f;
    float ohsum = 0.f;
    for (int n = blockIdx.x * blockDim.x + threadIdx.x; n < N; n += gridDim.x * blockDim.x) {
        float oh = onehot[n];
        float t = oh * dinv[n];
        ohsum += oh;
        const float4* sp = (const float4*)(s2 + (size_t)n * 32);
        const float4* gp = (const float4*)(g2 + (size_t)n * 32);
#pragma unroll
        for (int q = 0; q < 8; q++) {
            float4 sv = sp[q], gv = gp[q];
            acc[4 * q + 0] += t * (sv.x + gv.x);
            acc[4 * q + 1] += t * (sv.y + gv.y);
            acc[4 * q + 2] += t * (sv.z + gv.z);
            acc[4 * q + 3] += t * (sv.w + gv.w);
        }
    }
#pragma unroll
    for (int j = 0; j < 32; j++) {
        for (int off = 32; off > 0; off >>= 1) acc[j] += __shfl_down(acc[j], off);
    }
    for (int off = 32; off > 0; off >>= 1) ohsum += __shfl_down(ohsum, off);
    if ((threadIdx.x & 63) == 0) {
#pragma unroll
        for (int j = 0; j < 32; j++) atomicAdd(&out[j], acc[j] + b2[j] * ohsum);
    }
}

extern "C" void kernel_launch(void* const* d_in, const int* in_sizes, int n_in,
                              void* d_out, int out_size, void* d_ws, size_t ws_size,
                              hipStream_t stream) {
    const float* x      = (const float*)d_in[0];  // [48, N]
    const float* onehot = (const float*)d_in[1];  // [N]
    const float* W1     = (const float*)d_in[2];  // [48,48]
    const float* b1     = (const float*)d_in[3];  // [48]
    const float* W2     = (const float*)d_in[4];  // [48,32]
    const float* b2     = (const float*)d_in[5];  // [32]
    const int*   ei     = (const int*)d_in[6];    // [2,E] int32

    int N = in_sizes[1];
    int E = in_sizes[6] / 2;
    const int* row = ei;       // source
    const int* col = ei + E;   // target

    float* ws   = (float*)d_ws;
    int*   deg  = (int*)ws;                       // N
    float* s1   = ws + (size_t)N;                 // 48N
    float* s2   = s1 + (size_t)N * 48;            // 32N
    float* dinv = s2 + (size_t)N * 32;            // N
    float* g1   = dinv + (size_t)N;               // 48N
    float* g2   = g1 + (size_t)N * 48;            // 32N

    // zero the atomic targets (deg, s1, s2 are contiguous at front) and d_out
    hipMemsetAsync(d_ws, 0, (size_t)(1 + 48 + 32) * N * sizeof(float), stream);
    hipMemsetAsync(d_out, 0, (size_t)out_size * sizeof(float), stream);

    int be = (E + 255) / 256;
    int bn = (N + 255) / 256;
    k_degree<<<be, 256, 0, stream>>>(col, E, deg);
    k_gemm1<<<bn, 256, 0, stream>>>(x, W1, deg, dinv, g1, N);
    k_scatter<48><<<be, 256, 0, stream>>>(row, col, g1, s1, E);
    k_gemm2<<<bn, 256, 0, stream>>>(s1, g1, dinv, b1, W2, g2, N);
    k_scatter<32><<<be, 256, 0, stream>>>(row, col, g2, s2, E);
    k_final<<<256, 256, 0, stream>>>(s2, g2, dinv, onehot, b2, (float*)d_out, N);
}

// Round 2
// 786.366 us; speedup vs baseline: 8.9395x; 8.9395x over previous
//
#include <hip/hip_runtime.h>

// GCN 2-layer forward, CSR-gather formulation (no float atomics).
// Pipeline: degree hist -> gemm1(+dinv) -> exclusive scan -> CSR fill ->
//           gather48 (+ReLU +GEMM2 fused) -> gather32 (+dinv epilogue) -> final reduce.

__global__ void k_degree(const int* __restrict__ col, int E, int* __restrict__ deg) {
    int e = blockIdx.x * blockDim.x + threadIdx.x;
    if (e < E) atomicAdd(&deg[col[e]], 1);
}

// g1[n,:] = dinv[n] * (x.T @ W1)[n,:] ; dinv[n] = rsqrt(deg[n]+1)
__global__ void k_gemm1(const float* __restrict__ x, const float* __restrict__ W1,
                        const int* __restrict__ deg, float* __restrict__ dinv,
                        float* __restrict__ g1, int N) {
    __shared__ float Ws[48 * 48];
    for (int i = threadIdx.x; i < 48 * 48; i += blockDim.x) Ws[i] = W1[i];
    __syncthreads();
    int n = blockIdx.x * blockDim.x + threadIdx.x;
    if (n >= N) return;
    float acc[48];
#pragma unroll
    for (int j = 0; j < 48; j++) acc[j] = 0.f;
    for (int k = 0; k < 48; k++) {
        float xv = x[(size_t)k * N + n];  // coalesced across lanes
#pragma unroll
        for (int j = 0; j < 48; j++) acc[j] += xv * Ws[k * 48 + j];  // LDS broadcast
    }
    float dv = rsqrtf((float)(deg[n] + 1));
    dinv[n] = dv;
    float* gp = g1 + (size_t)n * 48;
#pragma unroll
    for (int j = 0; j < 48; j++) gp[j] = dv * acc[j];
}

// ---- exclusive scan of deg[N] -> start[N] (3-kernel hierarchical) ----
__global__ void k_scan1(const int* __restrict__ deg, int* __restrict__ part,
                        int* __restrict__ bsum, int N) {
    __shared__ int s[256];
    int n = blockIdx.x * 256 + threadIdx.x;
    int v = (n < N) ? deg[n] : 0;
    s[threadIdx.x] = v;
    __syncthreads();
    for (int off = 1; off < 256; off <<= 1) {
        int t = (threadIdx.x >= off) ? s[threadIdx.x - off] : 0;
        __syncthreads();
        s[threadIdx.x] += t;
        __syncthreads();
    }
    if (n < N) part[n] = s[threadIdx.x] - v;  // exclusive within block
    if (threadIdx.x == 255) bsum[blockIdx.x] = s[255];
}

__global__ void k_scan2(int* __restrict__ bsum, int nb) {  // nb <= 512
    __shared__ int s[512];
    int v = (threadIdx.x < nb) ? bsum[threadIdx.x] : 0;
    s[threadIdx.x] = v;
    __syncthreads();
    for (int off = 1; off < 512; off <<= 1) {
        int t = (threadIdx.x >= off) ? s[threadIdx.x - off] : 0;
        __syncthreads();
        s[threadIdx.x] += t;
        __syncthreads();
    }
    if (threadIdx.x < nb) bsum[threadIdx.x] = s[threadIdx.x] - v;  // exclusive
}

__global__ void k_scan3(const int* __restrict__ part, const int* __restrict__ bsum,
                        int* __restrict__ start, int* __restrict__ cursor, int N) {
    int n = blockIdx.x * 256 + threadIdx.x;
    if (n < N) {
        int v = part[n] + bsum[blockIdx.x];
        start[n] = v;
        cursor[n] = v;
    }
}

__global__ void k_fill(const int* __restrict__ row, const int* __restrict__ col, int E,
                       int* __restrict__ cursor, int* __restrict__ srcs) {
    int e = blockIdx.x * blockDim.x + threadIdx.x;
    if (e < E) {
        int pos = atomicAdd(&cursor[col[e]], 1);
        srcs[pos] = row[e];
    }
}

// Per node c (48-thread group): acc_f = sum over in-edges of g1[src,f] + g1[c,f];
// a1 = relu(dinv*acc + b1); then fused GEMM2: g2[c,j] = dinv * sum_k a1[k]*W2[k,j]
__launch_bounds__(192)
__global__ void k_gather48(const int* __restrict__ srcs, const int* __restrict__ start,
                           const int* __restrict__ deg, const float* __restrict__ g1,
                           const float* __restrict__ dinv, const float* __restrict__ b1,
                           const float* __restrict__ W2, float* __restrict__ g2, int N) {
    __shared__ float W2s[48 * 32];
    __shared__ float a1s[4][48];
    for (int i = threadIdx.x; i < 48 * 32; i += 192) W2s[i] = W2[i];
    int grp = threadIdx.x / 48, f = threadIdx.x % 48;
    int c = blockIdx.x * 4 + grp;
    float a = 0.f, dv = 0.f;
    if (c < N) {
        int beg = start[c], d = deg[c];
        float acc = 0.f;
        int i = 0;
        for (; i + 1 < d; i += 2) {  // 2-way unroll for 2 outstanding gathers
            int s0 = srcs[beg + i];
            int s1 = srcs[beg + i + 1];
            float v0 = g1[(size_t)s0 * 48 + f];
            float v1 = g1[(size_t)s1 * 48 + f];
            acc += v0 + v1;
        }
        if (i < d) acc += g1[(size_t)srcs[beg + i] * 48 + f];
        acc += g1[(size_t)c * 48 + f];  // self-loop
        dv = dinv[c];
        a = dv * acc + b1[f];
        a = a > 0.f ? a : 0.f;
    }
    a1s[grp][f] = a;
    __syncthreads();
    if (c < N && f < 32) {
        float acc2 = 0.f;
#pragma unroll
        for (int k = 0; k < 48; k++) acc2 += a1s[grp][k] * W2s[k * 32 + f];
        g2[(size_t)c * 32 + f] = dv * acc2;
    }
}

// h[c,f] = dinv[c] * (sum over in-edges g2[src,f] + g2[c,f])
__launch_bounds__(256)
__global__ void k_gather32(const int* __restrict__ srcs, const int* __restrict__ start,
                           const int* __restrict__ deg, const float* __restrict__ g2,
                           const float* __restrict__ dinv, float* __restrict__ h, int N) {
    int grp = threadIdx.x >> 5, f = threadIdx.x & 31;
    int c = blockIdx.x * 8 + grp;
    if (c >= N) return;
    int beg = start[c], d = deg[c];
    float acc = 0.f;
    int i = 0;
    for (; i + 1 < d; i += 2) {
        int s0 = srcs[beg + i];
        int s1 = srcs[beg + i + 1];
        float v0 = g2[(size_t)s0 * 32 + f];
        float v1 = g2[(size_t)s1 * 32 + f];
        acc += v0 + v1;
    }
    if (i < d) acc += g2[(size_t)srcs[beg + i] * 32 + f];
    acc += g2[(size_t)c * 32 + f];
    h[(size_t)c * 32 + f] = dinv[c] * acc;
}

// out[j] = sum_n onehot[n]*h[n,j] + b2[j]*sum_n onehot[n]
__global__ void k_final(const float* __restrict__ h, const float* __restrict__ onehot,
                        const float* __restrict__ b2, float* __restrict__ out, int N) {
    float acc[32];
#pragma unroll
    for (int j = 0; j < 32; j++) acc[j] = 0.f;
    float ohsum = 0.f;
    for (int n = blockIdx.x * blockDim.x + threadIdx.x; n < N; n += gridDim.x * blockDim.x) {
        float oh = onehot[n];
        ohsum += oh;
        const float4* hp = (const float4*)(h + (size_t)n * 32);
#pragma unroll
        for (int q = 0; q < 8; q++) {
            float4 hv = hp[q];
            acc[4 * q + 0] += oh * hv.x;
            acc[4 * q + 1] += oh * hv.y;
            acc[4 * q + 2] += oh * hv.z;
            acc[4 * q + 3] += oh * hv.w;
        }
    }
#pragma unroll
    for (int j = 0; j < 32; j++) {
        for (int off = 32; off > 0; off >>= 1) acc[j] += __shfl_down(acc[j], off);
    }
    for (int off = 32; off > 0; off >>= 1) ohsum += __shfl_down(ohsum, off);
    if ((threadIdx.x & 63) == 0) {
#pragma unroll
        for (int j = 0; j < 32; j++) atomicAdd(&out[j], acc[j] + b2[j] * ohsum);
    }
}

extern "C" void kernel_launch(void* const* d_in, const int* in_sizes, int n_in,
                              void* d_out, int out_size, void* d_ws, size_t ws_size,
                              hipStream_t stream) {
    const float* x      = (const float*)d_in[0];  // [48, N]
    const float* onehot = (const float*)d_in[1];  // [N]
    const float* W1     = (const float*)d_in[2];  // [48,48]
    const float* b1     = (const float*)d_in[3];  // [48]
    const float* W2     = (const float*)d_in[4];  // [48,32]
    const float* b2     = (const float*)d_in[5];  // [32]
    const int*   ei     = (const int*)d_in[6];    // [2,E] int32

    int N = in_sizes[1];
    int E = in_sizes[6] / 2;
    const int* row = ei;       // source
    const int* col = ei + E;   // target

    // ws layout (4B units)
    char* wsb = (char*)d_ws;
    int*   deg    = (int*)wsb;                         wsb += (size_t)N * 4;
    int*   part   = (int*)wsb;                         wsb += (size_t)N * 4;
    int*   bsum   = (int*)wsb;                         wsb += 512 * 4;
    int*   start  = (int*)wsb;                         wsb += (size_t)N * 4;
    int*   cursor = (int*)wsb;                         wsb += (size_t)N * 4;
    int*   srcs   = (int*)wsb;                         wsb += (size_t)E * 4;
    float* dinv   = (float*)wsb;                       wsb += (size_t)N * 4;
    float* g1     = (float*)wsb;                       wsb += (size_t)N * 48 * 4;
    float* g2     = (float*)wsb;                       wsb += (size_t)N * 32 * 4;
    float* h      = (float*)wsb;                       wsb += (size_t)N * 32 * 4;

    hipMemsetAsync(deg, 0, (size_t)N * 4, stream);
    hipMemsetAsync(d_out, 0, (size_t)out_size * sizeof(float), stream);

    int be = (E + 255) / 256;
    int bn = (N + 255) / 256;
    k_degree<<<be, 256, 0, stream>>>(col, E, deg);
    k_gemm1<<<bn, 256, 0, stream>>>(x, W1, deg, dinv, g1, N);
    k_scan1<<<bn, 256, 0, stream>>>(deg, part, bsum, N);
    k_scan2<<<1, 512, 0, stream>>>(bsum, bn);
    k_scan3<<<bn, 256, 0, stream>>>(part, bsum, start, cursor, N);
    k_fill<<<be, 256, 0, stream>>>(row, col, E, cursor, srcs);
    k_gather48<<<(N + 3) / 4, 192, 0, stream>>>(srcs, start, deg, g1, dinv, b1, W2, g2, N);
    k_gather32<<<(N + 7) / 8, 256, 0, stream>>>(srcs, start, deg, g2, dinv, h, N);
    k_final<<<256, 256, 0, stream>>>(h, onehot, b2, (float*)d_out, N);
}

// Round 3
// 470.711 us; speedup vs baseline: 14.9342x; 1.6706x over previous
//
#include <hip/hip_runtime.h>

// GCN 2-layer forward, CSR-gather formulation (no float atomics).
// Pipeline: degree hist -> gemm1(+dinv) -> exclusive scan -> CSR fill ->
//           gather48 (+ReLU +GEMM2 fused) -> gather32 (+dinv epilogue) -> final reduce.

__global__ void k_degree(const int* __restrict__ col, int E, int* __restrict__ deg) {
    int e = blockIdx.x * blockDim.x + threadIdx.x;
    if (e < E) atomicAdd(&deg[col[e]], 1);
}

// g1[n,:] = dinv[n] * (x.T @ W1)[n,:] ; dinv[n] = rsqrt(deg[n]+1)
__global__ void k_gemm1(const float* __restrict__ x, const float* __restrict__ W1,
                        const int* __restrict__ deg, float* __restrict__ dinv,
                        float* __restrict__ g1, int N) {
    __shared__ float Ws[48 * 48];
    for (int i = threadIdx.x; i < 48 * 48; i += blockDim.x) Ws[i] = W1[i];
    __syncthreads();
    int n = blockIdx.x * blockDim.x + threadIdx.x;
    if (n >= N) return;
    float acc[48];
#pragma unroll
    for (int j = 0; j < 48; j++) acc[j] = 0.f;
    for (int k = 0; k < 48; k++) {
        float xv = x[(size_t)k * N + n];  // coalesced across lanes
#pragma unroll
        for (int j = 0; j < 48; j++) acc[j] += xv * Ws[k * 48 + j];  // LDS broadcast
    }
    float dv = rsqrtf((float)(deg[n] + 1));
    dinv[n] = dv;
    float* gp = g1 + (size_t)n * 48;
#pragma unroll
    for (int j = 0; j < 48; j++) gp[j] = dv * acc[j];
}

// ---- exclusive scan of deg[N] -> start[N] (3-kernel hierarchical) ----
__global__ void k_scan1(const int* __restrict__ deg, int* __restrict__ part,
                        int* __restrict__ bsum, int N) {
    __shared__ int s[256];
    int n = blockIdx.x * 256 + threadIdx.x;
    int v = (n < N) ? deg[n] : 0;
    s[threadIdx.x] = v;
    __syncthreads();
    for (int off = 1; off < 256; off <<= 1) {
        int t = (threadIdx.x >= off) ? s[threadIdx.x - off] : 0;
        __syncthreads();
        s[threadIdx.x] += t;
        __syncthreads();
    }
    if (n < N) part[n] = s[threadIdx.x] - v;  // exclusive within block
    if (threadIdx.x == 255) bsum[blockIdx.x] = s[255];
}

__global__ void k_scan2(int* __restrict__ bsum, int nb) {  // nb <= 512
    __shared__ int s[512];
    int v = (threadIdx.x < nb) ? bsum[threadIdx.x] : 0;
    s[threadIdx.x] = v;
    __syncthreads();
    for (int off = 1; off < 512; off <<= 1) {
        int t = (threadIdx.x >= off) ? s[threadIdx.x - off] : 0;
        __syncthreads();
        s[threadIdx.x] += t;
        __syncthreads();
    }
    if (threadIdx.x < nb) bsum[threadIdx.x] = s[threadIdx.x] - v;  // exclusive
}

__global__ void k_scan3(const int* __restrict__ part, const int* __restrict__ bsum,
                        int* __restrict__ start, int* __restrict__ cursor, int N) {
    int n = blockIdx.x * 256 + threadIdx.x;
    if (n < N) {
        int v = part[n] + bsum[blockIdx.x];
        start[n] = v;
        cursor[n] = v;
    }
}

__global__ void k_fill(const int* __restrict__ row, const int* __restrict__ col, int E,
                       int* __restrict__ cursor, int* __restrict__ srcs) {
    int e = blockIdx.x * blockDim.x + threadIdx.x;
    if (e < E) {
        int pos = atomicAdd(&cursor[col[e]], 1);
        srcs[pos] = row[e];
    }
}

// Per node c (48-thread group): acc_f = sum over in-edges of g1[src,f] + g1[c,f];
// a1 = relu(dinv*acc + b1); then fused GEMM2: g2[c,j] = dinv * sum_k a1[k]*W2[k,j]
__launch_bounds__(192)
__global__ void k_gather48(const int* __restrict__ srcs, const int* __restrict__ start,
                           const int* __restrict__ deg, const float* __restrict__ g1,
                           const float* __restrict__ dinv, const float* __restrict__ b1,
                           const float* __restrict__ W2, float* __restrict__ g2, int N) {
    __shared__ float W2s[48 * 32];
    __shared__ float a1s[4][48];
    for (int i = threadIdx.x; i < 48 * 32; i += 192) W2s[i] = W2[i];
    int grp = threadIdx.x / 48, f = threadIdx.x % 48;
    int c = blockIdx.x * 4 + grp;
    float a = 0.f, dv = 0.f;
    if (c < N) {
        int beg = start[c], d = deg[c];
        float acc = 0.f;
        int i = 0;
        for (; i + 1 < d; i += 2) {  // 2-way unroll for 2 outstanding gathers
            int s0 = srcs[beg + i];
            int s1 = srcs[beg + i + 1];
            float v0 = g1[(size_t)s0 * 48 + f];
            float v1 = g1[(size_t)s1 * 48 + f];
            acc += v0 + v1;
        }
        if (i < d) acc += g1[(size_t)srcs[beg + i] * 48 + f];
        acc += g1[(size_t)c * 48 + f];  // self-loop
        dv = dinv[c];
        a = dv * acc + b1[f];
        a = a > 0.f ? a : 0.f;
    }
    a1s[grp][f] = a;
    __syncthreads();
    if (c < N && f < 32) {
        float acc2 = 0.f;
#pragma unroll
        for (int k = 0; k < 48; k++) acc2 += a1s[grp][k] * W2s[k * 32 + f];
        g2[(size_t)c * 32 + f] = dv * acc2;
    }
}

// h[c,f] = dinv[c] * (sum over in-edges g2[src,f] + g2[c,f])
__launch_bounds__(256)
__global__ void k_gather32(const int* __restrict__ srcs, const int* __restrict__ start,
                           const int* __restrict__ deg, const float* __restrict__ g2,
                           const float* __restrict__ dinv, float* __restrict__ h, int N) {
    int grp = threadIdx.x >> 5, f = threadIdx.x & 31;
    int c = blockIdx.x * 8 + grp;
    if (c >= N) return;
    int beg = start[c], d = deg[c];
    float acc = 0.f;
    int i = 0;
    for (; i + 1 < d; i += 2) {
        int s0 = srcs[beg + i];
        int s1 = srcs[beg + i + 1];
        float v0 = g2[(size_t)s0 * 32 + f];
        float v1 = g2[(size_t)s1 * 32 + f];
        acc += v0 + v1;
    }
    if (i < d) acc += g2[(size_t)srcs[beg + i] * 32 + f];
    acc += g2[(size_t)c * 32 + f];
    h[(size_t)c * 32 + f] = dinv[c] * acc;
}

// out[j] = sum_n onehot[n]*h[n,j] + b2[j]*sum_n onehot[n]
// Each thread owns feature f = tid&31, scalar accumulator; stride-32-aligned
// LDS tree reduce; ONE wave-wide 32-lane atomic instruction per block.
__global__ void k_final(const float* __restrict__ h, const float* __restrict__ onehot,
                        const float* __restrict__ b2, float* __restrict__ out, int N) {
    __shared__ float s[256];
    __shared__ float s2[256];
    int tid = threadIdx.x;
    float acc = 0.f, ohs = 0.f;
    int total = N * 32;
    int stride = gridDim.x * blockDim.x;  // multiple of 32 -> f stays tid&31
    for (int i = blockIdx.x * blockDim.x + tid; i < total; i += stride) {
        int node = i >> 5;
        float oh = onehot[node];
        acc += oh * h[i];
        if ((i & 31) == 0) ohs += oh;  // only f==0 lanes count ohsum
    }
    s[tid] = acc;
    s2[tid] = ohs;
    __syncthreads();
    for (int off = 128; off >= 32; off >>= 1) {
        if (tid < off) {
            s[tid] += s[tid + off];
            s2[tid] += s2[tid + off];
        }
        __syncthreads();
    }
    if (tid < 32) {
        // s[tid] = sum over all threads with f==tid; s2[0] = block ohsum
        atomicAdd(&out[tid], s[tid] + b2[tid] * s2[0]);
    }
}

extern "C" void kernel_launch(void* const* d_in, const int* in_sizes, int n_in,
                              void* d_out, int out_size, void* d_ws, size_t ws_size,
                              hipStream_t stream) {
    const float* x      = (const float*)d_in[0];  // [48, N]
    const float* onehot = (const float*)d_in[1];  // [N]
    const float* W1     = (const float*)d_in[2];  // [48,48]
    const float* b1     = (const float*)d_in[3];  // [48]
    const float* W2     = (const float*)d_in[4];  // [48,32]
    const float* b2     = (const float*)d_in[5];  // [32]
    const int*   ei     = (const int*)d_in[6];    // [2,E] int32

    int N = in_sizes[1];
    int E = in_sizes[6] / 2;
    const int* row = ei;       // source
    const int* col = ei + E;   // target

    // ws layout (4B units)
    char* wsb = (char*)d_ws;
    int*   deg    = (int*)wsb;                         wsb += (size_t)N * 4;
    int*   part   = (int*)wsb;                         wsb += (size_t)N * 4;
    int*   bsum   = (int*)wsb;                         wsb += 512 * 4;
    int*   start  = (int*)wsb;                         wsb += (size_t)N * 4;
    int*   cursor = (int*)wsb;                         wsb += (size_t)N * 4;
    int*   srcs   = (int*)wsb;                         wsb += (size_t)E * 4;
    float* dinv   = (float*)wsb;                       wsb += (size_t)N * 4;
    float* g1     = (float*)wsb;                       wsb += (size_t)N * 48 * 4;
    float* g2     = (float*)wsb;                       wsb += (size_t)N * 32 * 4;
    float* h      = (float*)wsb;                       wsb += (size_t)N * 32 * 4;

    hipMemsetAsync(deg, 0, (size_t)N * 4, stream);
    hipMemsetAsync(d_out, 0, (size_t)out_size * sizeof(float), stream);

    int be = (E + 255) / 256;
    int bn = (N + 255) / 256;
    k_degree<<<be, 256, 0, stream>>>(col, E, deg);
    k_gemm1<<<bn, 256, 0, stream>>>(x, W1, deg, dinv, g1, N);
    k_scan1<<<bn, 256, 0, stream>>>(deg, part, bsum, N);
    k_scan2<<<1, 512, 0, stream>>>(bsum, bn);
    k_scan3<<<bn, 256, 0, stream>>>(part, bsum, start, cursor, N);
    k_fill<<<be, 256, 0, stream>>>(row, col, E, cursor, srcs);
    k_gather48<<<(N + 3) / 4, 192, 0, stream>>>(srcs, start, deg, g1, dinv, b1, W2, g2, N);
    k_gather32<<<(N + 7) / 8, 256, 0, stream>>>(srcs, start, deg, g2, dinv, h, N);
    k_final<<<256, 256, 0, stream>>>(h, onehot, b2, (float*)d_out, N);
}